// Round 7
// baseline (254.781 us; speedup 1.0000x reference)
//
#include <hip/hip_runtime.h>
#include <hip/hip_bf16.h>
#include <stdint.h>

#define D_DIM 256
#define INV_T 14.285714285714286f  // 1/0.07

#define BM 256
#define BN 256
#define BK 32
#define NSTEP (D_DIM / BK)  // 8

typedef __bf16 bf16x8 __attribute__((ext_vector_type(8)));
typedef float f32x16 __attribute__((ext_vector_type(16)));

// ---------------------------------------------------------------------------
// Kernel A: normalization. One wave per row (float4 loads), 4 rows/block.
// Exact fp32 diagonal Sv, bf16 normalized outputs, rowsum zero-init.
// ---------------------------------------------------------------------------
__global__ __launch_bounds__(256) void lit_normalize(
    const float* __restrict__ X, const float* __restrict__ Y,
    __hip_bfloat16* __restrict__ Xb, __hip_bfloat16* __restrict__ Yb,
    float* __restrict__ Sv, float* __restrict__ rowsum)
{
    const int l = threadIdx.x & 63;
    const int row = blockIdx.x * 4 + (threadIdx.x >> 6);
    const size_t base = (size_t)row * D_DIM;
    const float4 x = ((const float4*)(X + base))[l];
    const float4 y = ((const float4*)(Y + base))[l];
    float nx = x.x * x.x + x.y * x.y + x.z * x.z + x.w * x.w;
    float ny = y.x * y.x + y.y * y.y + y.z * y.z + y.w * y.w;
    float dt = x.x * y.x + x.y * y.y + x.z * y.z + x.w * y.w;
    #pragma unroll
    for (int o = 1; o < 64; o <<= 1) {
        nx += __shfl_xor(nx, o);
        ny += __shfl_xor(ny, o);
        dt += __shfl_xor(dt, o);
    }
    const float ivx = 1.0f / fmaxf(sqrtf(nx), 1e-12f);
    const float ivy = 1.0f / fmaxf(sqrtf(ny), 1e-12f);

    __hip_bfloat16 hx0 = __float2bfloat16(x.x * ivx), hx1 = __float2bfloat16(x.y * ivx);
    __hip_bfloat16 hx2 = __float2bfloat16(x.z * ivx), hx3 = __float2bfloat16(x.w * ivx);
    __hip_bfloat16 hy0 = __float2bfloat16(y.x * ivy), hy1 = __float2bfloat16(y.y * ivy);
    __hip_bfloat16 hy2 = __float2bfloat16(y.z * ivy), hy3 = __float2bfloat16(y.w * ivy);
    ushort4 px, py;
    px.x = *(unsigned short*)&hx0; px.y = *(unsigned short*)&hx1;
    px.z = *(unsigned short*)&hx2; px.w = *(unsigned short*)&hx3;
    py.x = *(unsigned short*)&hy0; py.y = *(unsigned short*)&hy1;
    py.z = *(unsigned short*)&hy2; py.w = *(unsigned short*)&hy3;
    ((ushort4*)(Xb + base))[l] = px;
    ((ushort4*)(Yb + base))[l] = py;

    if (l == 0) {
        Sv[row] = (dt * ivx * ivy - 1.0f) * INV_T;  // exact diagonal logit
        rowsum[row] = 0.0f;
    }
}

// ---------------------------------------------------------------------------
// Kernel B: S = Xhat @ Yhat^T with SWAPPED operands (D = mfma(Yf, Xf), so
// D[m=j][n=i] -> j-reduction is in-thread), fused exp/rowsum epilogue.
// 256x256 tile, BK=32, 8 waves (wi=w>>2: 2 i-halves of 128; wj=w&3: 4
// j-quarters of 64), 32x32x16 bf16 MFMA, acc[fj:2][fi:4].
// Double-buffered 2x32KB LDS, compiler-friendly pipeline, ONE barrier/K-step:
//   ds_read cur-buf frags -> regs; issue STAGE(next buf); MFMA; __syncthreads.
// Compiler sinks its vmcnt(0) drain to just before the barrier => prefetch
// latency hides under the MFMA cluster. No inline asm / fences (round-4/5
// lesson: the per-block __threadfence L2-writeback storm was the 3.5x
// regression, NOT this loop shape).
// LDS swizzle: physical 16B slot = g ^ ((row>>1)&3), realized on the write
// side by pre-swizzling the global source (global_load_lds dest linear).
// Epilogue: disjoint per-wave rowpart slots, plain stores (no LDS atomics).
// ---------------------------------------------------------------------------
__global__ __launch_bounds__(512, 2) void lit_gemm_rowsum(
    const __hip_bfloat16* __restrict__ Xb, const __hip_bfloat16* __restrict__ Yb,
    float* __restrict__ rowsum)
{
    __shared__ char lds[2 * 32768];  // [buf][X 16KB | Y 16KB]

    const int tid = (int)threadIdx.x;
    const int l   = tid & 63;
    const int w   = tid >> 6;    // 0..7
    const int wi  = w >> 2;      // 0..1  (i-half: 128 rows)
    const int wj  = w & 3;       // 0..3  (j-quarter: 64 rows)

    // XCD-aware bijective swizzle (nwg = 4096, %8 == 0)
    const int nx  = (int)gridDim.x;
    const int bid = (int)blockIdx.y * nx + (int)blockIdx.x;
    const int cpx = (nx * (int)gridDim.y) >> 3;
    const int logical = (bid & 7) * cpx + (bid >> 3);
    const int bi = logical / nx;
    const int bj = logical % nx;
    const int iBase = bi * BM;
    const int jBase = bj * BN;

    f32x16 acc[2][4];
    #pragma unroll
    for (int a = 0; a < 2; ++a)
        #pragma unroll
        for (int b = 0; b < 4; ++b)
            #pragma unroll
            for (int r = 0; r < 16; ++r)
                acc[a][b][r] = 0.f;

    // Staging: 32 chunks of 16 rows x 64B = 1KB; wave w owns chunks w*4..w*4+3.
    // Chunks 0..15 = X rows 0..255; chunks 16..31 = Y rows 0..255.
    const int rq = l >> 2;   // row within chunk
    const int sl = l & 3;    // 16B slot within a 64B row
    const char* src[4];
    int dst[4];
    #pragma unroll
    for (int c = 0; c < 4; ++c) {
        const int g    = w * 4 + c;
        const int isY  = g >> 4;
        const int r16  = (g & 15) * 16;
        const int row  = r16 + rq;
        const int slot = sl ^ ((row >> 1) & 3);  // pre-swizzled source slot
        const char* base = isY ? (const char*)Yb + (size_t)jBase * (D_DIM * 2)
                               : (const char*)Xb + (size_t)iBase * (D_DIM * 2);
        src[c] = base + (size_t)row * (D_DIM * 2) + slot * 16;
        dst[c] = isY * 16384 + r16 * 64;
    }

#define STAGE(buf, t)                                                              \
    {                                                                              \
        _Pragma("unroll")                                                          \
        for (int c = 0; c < 4; ++c)                                                \
            __builtin_amdgcn_global_load_lds(                                      \
                (const __attribute__((address_space(1))) void*)(src[c] + (t) * (BK * 2)), \
                (__attribute__((address_space(3))) void*)(lds + (buf) * 32768 + dst[c]),  \
                16, 0, 0);                                                         \
    }

    STAGE(0, 0);
    __syncthreads();   // buf0 staged

    #pragma unroll
    for (int t = 0; t < NSTEP; ++t) {
        const char* Xs = lds + (t & 1) * 32768;
        const char* Ys = Xs + 16384;
        const int lr = l & 31;

        // 1) read this tile's fragments into registers (compile-time indices)
        bf16x8 af[2][2], bg[2][4];
        #pragma unroll
        for (int kk = 0; kk < 2; ++kk) {
            // logical 16B k-slot g = kk*2 + (l>>5); physical = g ^ ((row>>1)&3)
            const int sx = ((kk * 2 + (l >> 5)) ^ ((l >> 1) & 3)) * 16;
            af[kk][0] = *(const bf16x8*)(Ys + (wj * 64 +  0 + lr) * 64 + sx);
            af[kk][1] = *(const bf16x8*)(Ys + (wj * 64 + 32 + lr) * 64 + sx);
            bg[kk][0] = *(const bf16x8*)(Xs + (wi * 128 +  0 + lr) * 64 + sx);
            bg[kk][1] = *(const bf16x8*)(Xs + (wi * 128 + 32 + lr) * 64 + sx);
            bg[kk][2] = *(const bf16x8*)(Xs + (wi * 128 + 64 + lr) * 64 + sx);
            bg[kk][3] = *(const bf16x8*)(Xs + (wi * 128 + 96 + lr) * 64 + sx);
        }

        // 2) prefetch next K-tile into the other buffer
        if (t < NSTEP - 1) STAGE((t + 1) & 1, t + 1);

        // 3) MFMA cluster (prefetch latency hides under this)
        #pragma unroll
        for (int kk = 0; kk < 2; ++kk) {
            acc[0][0] = __builtin_amdgcn_mfma_f32_32x32x16_bf16(af[kk][0], bg[kk][0], acc[0][0], 0, 0, 0);
            acc[0][1] = __builtin_amdgcn_mfma_f32_32x32x16_bf16(af[kk][0], bg[kk][1], acc[0][1], 0, 0, 0);
            acc[0][2] = __builtin_amdgcn_mfma_f32_32x32x16_bf16(af[kk][0], bg[kk][2], acc[0][2], 0, 0, 0);
            acc[0][3] = __builtin_amdgcn_mfma_f32_32x32x16_bf16(af[kk][0], bg[kk][3], acc[0][3], 0, 0, 0);
            acc[1][0] = __builtin_amdgcn_mfma_f32_32x32x16_bf16(af[kk][1], bg[kk][0], acc[1][0], 0, 0, 0);
            acc[1][1] = __builtin_amdgcn_mfma_f32_32x32x16_bf16(af[kk][1], bg[kk][1], acc[1][1], 0, 0, 0);
            acc[1][2] = __builtin_amdgcn_mfma_f32_32x32x16_bf16(af[kk][1], bg[kk][2], acc[1][2], 0, 0, 0);
            acc[1][3] = __builtin_amdgcn_mfma_f32_32x32x16_bf16(af[kk][1], bg[kk][3], acc[1][3], 0, 0, 0);
        }

        // 4) single rendezvous: reads of buf[t&1] done + stage(t+1) drained
        __syncthreads();
    }

    // ---- epilogue: rowsum_i += sum_j exp((S[i][j]-1)/tau) ----
    // D layout (32x32): n=i = lane&31; m=j = (reg&3)+8*(reg>>2)+4*(lane>>5).
    float part[4];
    #pragma unroll
    for (int fi = 0; fi < 4; ++fi) {
        float s = 0.f;
        #pragma unroll
        for (int fj = 0; fj < 2; ++fj)
            #pragma unroll
            for (int r = 0; r < 16; ++r)
                s += __expf(fmaf(acc[fj][fi][r], INV_T, -INV_T));
        s += __shfl_xor(s, 32);  // combine the two j-column-halves (lane>>5)
        part[fi] = s;
    }
    // Conflict-free combine: wave writes its disjoint slot rowpart4[wj][row]
    // (plain stores, lanes 0..31 -> consecutive banks), then 256 threads sum 4.
    float (*rowpart4)[BM] = (float (*)[BM])lds;  // 4 KB, free after last barrier
    if (l < 32) {
        #pragma unroll
        for (int fi = 0; fi < 4; ++fi)
            rowpart4[wj][wi * 128 + fi * 32 + l] = part[fi];
    }
    __syncthreads();
    if (tid < BM) {
        const float v = rowpart4[0][tid] + rowpart4[1][tid]
                      + rowpart4[2][tid] + rowpart4[3][tid];
        atomicAdd(&rowsum[iBase + tid], v);
    }
}

// ---------------------------------------------------------------------------
// Kernel C: loss = -mean(Sv - log(rowsum)). Single block, 1024 threads.
// ---------------------------------------------------------------------------
__global__ __launch_bounds__(1024) void lit_finish(
    const float* __restrict__ Sv, const float* __restrict__ rowsum,
    float* __restrict__ out, int N)
{
    float s = 0.f;
    for (int i = threadIdx.x; i < N; i += 1024)
        s += Sv[i] - __logf(rowsum[i]);
    #pragma unroll
    for (int o = 1; o < 64; o <<= 1) s += __shfl_xor(s, o);
    __shared__ float sred[16];
    if ((threadIdx.x & 63) == 0) sred[threadIdx.x >> 6] = s;
    __syncthreads();
    if (threadIdx.x == 0) {
        float tot = 0.f;
        #pragma unroll
        for (int k = 0; k < 16; ++k) tot += sred[k];
        out[0] = -tot / (float)N;
    }
}

// ---------------------------------------------------------------------------
extern "C" void kernel_launch(void* const* d_in, const int* in_sizes, int n_in,
                              void* d_out, int out_size, void* d_ws, size_t ws_size,
                              hipStream_t stream)
{
    const float* X = (const float*)d_in[0];
    const float* Y = (const float*)d_in[1];
    const int N = in_sizes[0] / D_DIM;  // 16384

    char* ws = (char*)d_ws;
    __hip_bfloat16* Xb = (__hip_bfloat16*)ws;
    __hip_bfloat16* Yb = (__hip_bfloat16*)(ws + (size_t)N * D_DIM * 2);
    float* Sv     = (float*)(ws + (size_t)N * D_DIM * 4);
    float* rowsum = (float*)(ws + (size_t)N * D_DIM * 4 + (size_t)N * 4);

    lit_normalize<<<N / 4, 256, 0, stream>>>(X, Y, Xb, Yb, Sv, rowsum);
    dim3 grid(N / BN, N / BM);
    lit_gemm_rowsum<<<grid, 512, 0, stream>>>(Xb, Yb, rowsum);
    lit_finish<<<1, 1024, 0, stream>>>(Sv, rowsum, (float*)d_out, N);
}

// Round 8
// 246.064 us; speedup vs baseline: 1.0354x; 1.0354x over previous
//
#include <hip/hip_runtime.h>
#include <hip/hip_bf16.h>
#include <stdint.h>

#define D_DIM 256
#define INV_T 14.285714285714286f  // 1/0.07

#define BM 256
#define BN 256
#define BK 32
#define NSTEP (D_DIM / BK)  // 8

typedef __bf16 bf16x8 __attribute__((ext_vector_type(8)));
typedef float f32x16 __attribute__((ext_vector_type(16)));

// ---------------------------------------------------------------------------
// Kernel A: normalization. One wave per row (float4 loads), 4 rows/block.
// Exact fp32 diagonal Sv, bf16 normalized outputs, rowsum zero-init.
// ---------------------------------------------------------------------------
__global__ __launch_bounds__(256) void lit_normalize(
    const float* __restrict__ X, const float* __restrict__ Y,
    __hip_bfloat16* __restrict__ Xb, __hip_bfloat16* __restrict__ Yb,
    float* __restrict__ Sv, float* __restrict__ rowsum)
{
    const int l = threadIdx.x & 63;
    const int row = blockIdx.x * 4 + (threadIdx.x >> 6);
    const size_t base = (size_t)row * D_DIM;
    const float4 x = ((const float4*)(X + base))[l];
    const float4 y = ((const float4*)(Y + base))[l];
    float nx = x.x * x.x + x.y * x.y + x.z * x.z + x.w * x.w;
    float ny = y.x * y.x + y.y * y.y + y.z * y.z + y.w * y.w;
    float dt = x.x * y.x + x.y * y.y + x.z * y.z + x.w * y.w;
    #pragma unroll
    for (int o = 1; o < 64; o <<= 1) {
        nx += __shfl_xor(nx, o);
        ny += __shfl_xor(ny, o);
        dt += __shfl_xor(dt, o);
    }
    const float ivx = 1.0f / fmaxf(sqrtf(nx), 1e-12f);
    const float ivy = 1.0f / fmaxf(sqrtf(ny), 1e-12f);

    __hip_bfloat16 hx0 = __float2bfloat16(x.x * ivx), hx1 = __float2bfloat16(x.y * ivx);
    __hip_bfloat16 hx2 = __float2bfloat16(x.z * ivx), hx3 = __float2bfloat16(x.w * ivx);
    __hip_bfloat16 hy0 = __float2bfloat16(y.x * ivy), hy1 = __float2bfloat16(y.y * ivy);
    __hip_bfloat16 hy2 = __float2bfloat16(y.z * ivy), hy3 = __float2bfloat16(y.w * ivy);
    ushort4 px, py;
    px.x = *(unsigned short*)&hx0; px.y = *(unsigned short*)&hx1;
    px.z = *(unsigned short*)&hx2; px.w = *(unsigned short*)&hx3;
    py.x = *(unsigned short*)&hy0; py.y = *(unsigned short*)&hy1;
    py.z = *(unsigned short*)&hy2; py.w = *(unsigned short*)&hy3;
    ((ushort4*)(Xb + base))[l] = px;
    ((ushort4*)(Yb + base))[l] = py;

    if (l == 0) {
        Sv[row] = (dt * ivx * ivy - 1.0f) * INV_T;  // exact diagonal logit
        rowsum[row] = 0.0f;
    }
}

// ---------------------------------------------------------------------------
// Kernel B: same geometry/compute as round 7 (proven correct), new sync:
// counted vmcnt + raw barriers so prefetched loads SURVIVE across barriers
// (T4). r5-vs-r7 A/B proved the old r4 regression was the __threadfence
// poison, not this structure — this is the clean re-test.
// Per tile t (BK=32, 8 tiles, buffers by t&1):
//   [entry] s_waitcnt vmcnt(4) (t landed; t+1 still in flight) ; s_barrier
//   compute: 12 ds_read_b128 -> 16 MFMA (setprio-wrapped), compiler-scheduled
//   [exit]  s_waitcnt lgkmcnt(0) ; s_barrier  (all waves done reading buf)
//   STAGE(t+2) -> buf[t&1]   (issued AFTER the exit barrier: no overwrite race)
// Last tile uses vmcnt(0) (its successor was never staged).
// asm "memory" clobbers fence all LDS/global ops; global_load_lds (side-
// effecting builtin) cannot hoist above the volatile asm / barrier.
// ---------------------------------------------------------------------------
__global__ __launch_bounds__(512, 2) void lit_gemm_rowsum(
    const __hip_bfloat16* __restrict__ Xb, const __hip_bfloat16* __restrict__ Yb,
    float* __restrict__ rowsum)
{
    __shared__ char lds[2 * 32768];  // [buf][X 16KB | Y 16KB]

    const int tid = (int)threadIdx.x;
    const int l   = tid & 63;
    const int w   = tid >> 6;    // 0..7
    const int wi  = w >> 2;      // 0..1  (i-half: 128 rows)
    const int wj  = w & 3;       // 0..3  (j-quarter: 64 rows)

    // XCD-aware bijective swizzle (nwg = 4096, %8 == 0)
    const int nx  = (int)gridDim.x;
    const int bid = (int)blockIdx.y * nx + (int)blockIdx.x;
    const int cpx = (nx * (int)gridDim.y) >> 3;
    const int logical = (bid & 7) * cpx + (bid >> 3);
    const int bi = logical / nx;
    const int bj = logical % nx;
    const int iBase = bi * BM;
    const int jBase = bj * BN;

    f32x16 acc[2][4];
    #pragma unroll
    for (int a = 0; a < 2; ++a)
        #pragma unroll
        for (int b = 0; b < 4; ++b)
            #pragma unroll
            for (int r = 0; r < 16; ++r)
                acc[a][b][r] = 0.f;

    // Staging: 32 chunks of 16 rows x 64B = 1KB; wave w owns chunks w*4..w*4+3.
    // Chunks 0..15 = X rows 0..255; chunks 16..31 = Y rows 0..255.
    const int rq = l >> 2;   // row within chunk
    const int sl = l & 3;    // 16B slot within a 64B row
    const char* src[4];
    int dst[4];
    #pragma unroll
    for (int c = 0; c < 4; ++c) {
        const int g    = w * 4 + c;
        const int isY  = g >> 4;
        const int r16  = (g & 15) * 16;
        const int row  = r16 + rq;
        const int slot = sl ^ ((row >> 1) & 3);  // pre-swizzled source slot
        const char* base = isY ? (const char*)Yb + (size_t)jBase * (D_DIM * 2)
                               : (const char*)Xb + (size_t)iBase * (D_DIM * 2);
        src[c] = base + (size_t)row * (D_DIM * 2) + slot * 16;
        dst[c] = isY * 16384 + r16 * 64;
    }

#define STAGE(buf, t)                                                              \
    {                                                                              \
        _Pragma("unroll")                                                          \
        for (int c = 0; c < 4; ++c)                                                \
            __builtin_amdgcn_global_load_lds(                                      \
                (const __attribute__((address_space(1))) void*)(src[c] + (t) * (BK * 2)), \
                (__attribute__((address_space(3))) void*)(lds + (buf) * 32768 + dst[c]),  \
                16, 0, 0);                                                         \
    }

    STAGE(0, 0);   // tile 0 -> buf0
    STAGE(1, 1);   // tile 1 -> buf1   (8 loads/thread outstanding)

    #pragma unroll
    for (int t = 0; t < NSTEP; ++t) {
        // ---- tile entry: own tile landed; successor (if any) stays in flight
        if (t < NSTEP - 1) {
            asm volatile("s_waitcnt vmcnt(4)" ::: "memory");
        } else {
            asm volatile("s_waitcnt vmcnt(0)" ::: "memory");
        }
        __builtin_amdgcn_s_barrier();   // all waves' tile-t staging visible

        const char* Xs = lds + (t & 1) * 32768;
        const char* Ys = Xs + 16384;
        const int lr = l & 31;

        // fragments (compile-time indices); compiler inserts exact lgkm waits
        bf16x8 af[2][2], bg[2][4];
        #pragma unroll
        for (int kk = 0; kk < 2; ++kk) {
            // logical 16B k-slot g = kk*2 + (l>>5); physical = g ^ ((row>>1)&3)
            const int sx = ((kk * 2 + (l >> 5)) ^ ((l >> 1) & 3)) * 16;
            af[kk][0] = *(const bf16x8*)(Ys + (wj * 64 +  0 + lr) * 64 + sx);
            af[kk][1] = *(const bf16x8*)(Ys + (wj * 64 + 32 + lr) * 64 + sx);
            bg[kk][0] = *(const bf16x8*)(Xs + (wi * 128 +  0 + lr) * 64 + sx);
            bg[kk][1] = *(const bf16x8*)(Xs + (wi * 128 + 32 + lr) * 64 + sx);
            bg[kk][2] = *(const bf16x8*)(Xs + (wi * 128 + 64 + lr) * 64 + sx);
            bg[kk][3] = *(const bf16x8*)(Xs + (wi * 128 + 96 + lr) * 64 + sx);
        }
        #pragma unroll
        for (int kk = 0; kk < 2; ++kk) {
            __builtin_amdgcn_s_setprio(1);
            acc[0][0] = __builtin_amdgcn_mfma_f32_32x32x16_bf16(af[kk][0], bg[kk][0], acc[0][0], 0, 0, 0);
            acc[0][1] = __builtin_amdgcn_mfma_f32_32x32x16_bf16(af[kk][0], bg[kk][1], acc[0][1], 0, 0, 0);
            acc[0][2] = __builtin_amdgcn_mfma_f32_32x32x16_bf16(af[kk][0], bg[kk][2], acc[0][2], 0, 0, 0);
            acc[0][3] = __builtin_amdgcn_mfma_f32_32x32x16_bf16(af[kk][0], bg[kk][3], acc[0][3], 0, 0, 0);
            acc[1][0] = __builtin_amdgcn_mfma_f32_32x32x16_bf16(af[kk][1], bg[kk][0], acc[1][0], 0, 0, 0);
            acc[1][1] = __builtin_amdgcn_mfma_f32_32x32x16_bf16(af[kk][1], bg[kk][1], acc[1][1], 0, 0, 0);
            acc[1][2] = __builtin_amdgcn_mfma_f32_32x32x16_bf16(af[kk][1], bg[kk][2], acc[1][2], 0, 0, 0);
            acc[1][3] = __builtin_amdgcn_mfma_f32_32x32x16_bf16(af[kk][1], bg[kk][3], acc[1][3], 0, 0, 0);
            __builtin_amdgcn_s_setprio(0);
        }

        // ---- tile exit: all waves' reads of buf[t&1] retired, then reuse it
        asm volatile("s_waitcnt lgkmcnt(0)" ::: "memory");
        __builtin_amdgcn_s_barrier();
        if (t + 2 < NSTEP) STAGE(t & 1, t + 2);   // tile t+2 -> buf[t&1]
    }

    // ---- epilogue: rowsum_i += sum_j exp((S[i][j]-1)/tau) ----
    // D layout (32x32): n=i = lane&31; m=j = (reg&3)+8*(reg>>2)+4*(lane>>5).
    float part[4];
    #pragma unroll
    for (int fi = 0; fi < 4; ++fi) {
        float s = 0.f;
        #pragma unroll
        for (int fj = 0; fj < 2; ++fj)
            #pragma unroll
            for (int r = 0; r < 16; ++r)
                s += __expf(fmaf(acc[fj][fi][r], INV_T, -INV_T));
        s += __shfl_xor(s, 32);  // combine the two j-column-halves (lane>>5)
        part[fi] = s;
    }
    // Conflict-free combine: wave writes its disjoint slot rowpart4[wj][row]
    // (plain stores, lanes 0..31 -> consecutive banks), then 256 threads sum 4.
    float (*rowpart4)[BM] = (float (*)[BM])lds;  // buf0 region, reads all retired
    if (l < 32) {
        #pragma unroll
        for (int fi = 0; fi < 4; ++fi)
            rowpart4[wj][wi * 128 + fi * 32 + l] = part[fi];
    }
    __syncthreads();
    if (tid < BM) {
        const float v = rowpart4[0][tid] + rowpart4[1][tid]
                      + rowpart4[2][tid] + rowpart4[3][tid];
        atomicAdd(&rowsum[iBase + tid], v);
    }
}

// ---------------------------------------------------------------------------
// Kernel C: loss = -mean(Sv - log(rowsum)). Single block, 1024 threads.
// ---------------------------------------------------------------------------
__global__ __launch_bounds__(1024) void lit_finish(
    const float* __restrict__ Sv, const float* __restrict__ rowsum,
    float* __restrict__ out, int N)
{
    float s = 0.f;
    for (int i = threadIdx.x; i < N; i += 1024)
        s += Sv[i] - __logf(rowsum[i]);
    #pragma unroll
    for (int o = 1; o < 64; o <<= 1) s += __shfl_xor(s, o);
    __shared__ float sred[16];
    if ((threadIdx.x & 63) == 0) sred[threadIdx.x >> 6] = s;
    __syncthreads();
    if (threadIdx.x == 0) {
        float tot = 0.f;
        #pragma unroll
        for (int k = 0; k < 16; ++k) tot += sred[k];
        out[0] = -tot / (float)N;
    }
}

// ---------------------------------------------------------------------------
extern "C" void kernel_launch(void* const* d_in, const int* in_sizes, int n_in,
                              void* d_out, int out_size, void* d_ws, size_t ws_size,
                              hipStream_t stream)
{
    const float* X = (const float*)d_in[0];
    const float* Y = (const float*)d_in[1];
    const int N = in_sizes[0] / D_DIM;  // 16384

    char* ws = (char*)d_ws;
    __hip_bfloat16* Xb = (__hip_bfloat16*)ws;
    __hip_bfloat16* Yb = (__hip_bfloat16*)(ws + (size_t)N * D_DIM * 2);
    float* Sv     = (float*)(ws + (size_t)N * D_DIM * 4);
    float* rowsum = (float*)(ws + (size_t)N * D_DIM * 4 + (size_t)N * 4);

    lit_normalize<<<N / 4, 256, 0, stream>>>(X, Y, Xb, Yb, Sv, rowsum);
    dim3 grid(N / BN, N / BM);
    lit_gemm_rowsum<<<grid, 512, 0, stream>>>(Xb, Yb, rowsum);
    lit_finish<<<1, 1024, 0, stream>>>(Sv, rowsum, (float*)d_out, N);
}

// Round 9
// 230.710 us; speedup vs baseline: 1.1043x; 1.0665x over previous
//
#include <hip/hip_runtime.h>
#include <hip/hip_bf16.h>
#include <stdint.h>

#define D_DIM 256
#define INV_T 14.285714285714286f  // 1/0.07

#define BM 128   // i-rows per block
#define BN 128   // j-rows per block
#define BK 64
#define NSTEP (D_DIM / BK)  // 4

typedef __bf16 bf16x8 __attribute__((ext_vector_type(8)));
typedef float f32x4 __attribute__((ext_vector_type(4)));

// ---------------------------------------------------------------------------
// Kernel A: normalization. One wave per row (float4 loads), 4 rows/block.
// Exact fp32 diagonal Sv, bf16 normalized outputs, rowsum zero-init.
// ---------------------------------------------------------------------------
__global__ __launch_bounds__(256) void lit_normalize(
    const float* __restrict__ X, const float* __restrict__ Y,
    __hip_bfloat16* __restrict__ Xb, __hip_bfloat16* __restrict__ Yb,
    float* __restrict__ Sv, float* __restrict__ rowsum)
{
    const int l = threadIdx.x & 63;
    const int row = blockIdx.x * 4 + (threadIdx.x >> 6);
    const size_t base = (size_t)row * D_DIM;
    const float4 x = ((const float4*)(X + base))[l];
    const float4 y = ((const float4*)(Y + base))[l];
    float nx = x.x * x.x + x.y * x.y + x.z * x.z + x.w * x.w;
    float ny = y.x * y.x + y.y * y.y + y.z * y.z + y.w * y.w;
    float dt = x.x * y.x + x.y * y.y + x.z * y.z + x.w * y.w;
    #pragma unroll
    for (int o = 1; o < 64; o <<= 1) {
        nx += __shfl_xor(nx, o);
        ny += __shfl_xor(ny, o);
        dt += __shfl_xor(dt, o);
    }
    const float ivx = 1.0f / fmaxf(sqrtf(nx), 1e-12f);
    const float ivy = 1.0f / fmaxf(sqrtf(ny), 1e-12f);

    __hip_bfloat16 hx0 = __float2bfloat16(x.x * ivx), hx1 = __float2bfloat16(x.y * ivx);
    __hip_bfloat16 hx2 = __float2bfloat16(x.z * ivx), hx3 = __float2bfloat16(x.w * ivx);
    __hip_bfloat16 hy0 = __float2bfloat16(y.x * ivy), hy1 = __float2bfloat16(y.y * ivy);
    __hip_bfloat16 hy2 = __float2bfloat16(y.z * ivy), hy3 = __float2bfloat16(y.w * ivy);
    ushort4 px, py;
    px.x = *(unsigned short*)&hx0; px.y = *(unsigned short*)&hx1;
    px.z = *(unsigned short*)&hx2; px.w = *(unsigned short*)&hx3;
    py.x = *(unsigned short*)&hy0; py.y = *(unsigned short*)&hy1;
    py.z = *(unsigned short*)&hy2; py.w = *(unsigned short*)&hy3;
    ((ushort4*)(Xb + base))[l] = px;
    ((ushort4*)(Yb + base))[l] = py;

    if (l == 0) {
        Sv[row] = (dt * ivx * ivy - 1.0f) * INV_T;  // exact diagonal logit
        rowsum[row] = 0.0f;
    }
}

// ---------------------------------------------------------------------------
// Kernel B: the round-1/m97-proven 128x128 structure (0 bank conflicts
// measured) with SWAPPED operands: D = mfma(Y_frag, X_frag) so
// D[m=j][n=i] -> j-reduction (rowsum of exp) is in-thread.
// 4 waves (wj = w>>1: 2 j-halves of 64; wi = w&1: 2 i-halves of 64),
// 16x16x32 bf16 MFMA, 4x4 fragments/wave (MFMA:ds_read ratio 2.0),
// BK=64 single 32KB buffer, 2 __syncthreads per K-step (simple 2-barrier
// loop; guide m103: 128-tile is the right size for this structure),
// 4 blocks/CU for cross-block latency hiding (m114).
// LDS swizzle: physical 16B slot = g ^ (row&7), realized write-side by
// pre-swizzling the global source (global_load_lds dest linear; rule #21).
// ---------------------------------------------------------------------------
__global__ __launch_bounds__(256, 4) void lit_gemm_rowsum(
    const __hip_bfloat16* __restrict__ Xb, const __hip_bfloat16* __restrict__ Yb,
    float* __restrict__ rowsum)
{
    __shared__ char lds[2 * BM * BK * 2];  // Xs 16KB | Ys 16KB
    char* Xs = lds;
    char* Ys = lds + BM * BK * 2;

    const int tid = (int)threadIdx.x;
    const int l   = tid & 63;
    const int w   = tid >> 6;    // 0..3
    const int wj  = w >> 1;      // 0..1  (j-half: 64 rows of Y)
    const int wi  = w & 1;       // 0..1  (i-half: 64 rows of X)
    const int fr  = l & 15;      // fragment row/col within 16
    const int kg  = l >> 4;      // k-group (8 contiguous k of 32)

    // XCD-aware bijective swizzle (nwg = 16384, %8 == 0)
    const int nx  = (int)gridDim.x;
    const int bid = (int)blockIdx.y * nx + (int)blockIdx.x;
    const int cpx = (nx * (int)gridDim.y) >> 3;
    const int logical = (bid & 7) * cpx + (bid >> 3);
    const int bi = logical / nx;
    const int bj = logical % nx;
    const int iBase = bi * BM;
    const int jBase = bj * BN;

    f32x4 acc[4][4];   // [mj][ni]
    const f32x4 zero = {0.f, 0.f, 0.f, 0.f};
    #pragma unroll
    for (int a = 0; a < 4; ++a)
        #pragma unroll
        for (int b = 0; b < 4; ++b)
            acc[a][b] = zero;

    // Staging (round-1 verified): per K-step each wave issues 8 gloads;
    // wave w owns X rows w*32..w*32+31 and Y rows w*32..w*32+31.
    const int rq = l >> 3;   // row within an 8-row chunk
    const int sl = l & 7;    // 16B slot within a 128B row
    const char* srcX[4]; const char* srcY[4];
    int dstX[4], dstY[4];
    #pragma unroll
    for (int i = 0; i < 4; ++i) {
        const int row  = w * 32 + i * 8 + rq;
        const int slot = sl ^ (row & 7);  // pre-swizzled source slot
        srcX[i] = (const char*)Xb + (size_t)(iBase + row) * (D_DIM * 2) + slot * 16;
        srcY[i] = (const char*)Yb + (size_t)(jBase + row) * (D_DIM * 2) + slot * 16;
        dstX[i] = (w * 32 + i * 8) * 128;
        dstY[i] = BM * BK * 2 + (w * 32 + i * 8) * 128;
    }

    #pragma unroll
    for (int t = 0; t < NSTEP; ++t) {
        #pragma unroll
        for (int i = 0; i < 4; ++i) {
            __builtin_amdgcn_global_load_lds(
                (const __attribute__((address_space(1))) void*)(srcX[i] + t * (BK * 2)),
                (__attribute__((address_space(3))) void*)(lds + dstX[i]), 16, 0, 0);
            __builtin_amdgcn_global_load_lds(
                (const __attribute__((address_space(1))) void*)(srcY[i] + t * (BK * 2)),
                (__attribute__((address_space(3))) void*)(lds + dstY[i]), 16, 0, 0);
        }
        __syncthreads();

        #pragma unroll
        for (int kk = 0; kk < 2; ++kk) {
            // logical 16B k-slot g = kk*4 + kg; physical = g ^ (row&7); row&7 = fr&7
            bf16x8 af[4], bg[4];
            #pragma unroll
            for (int mj = 0; mj < 4; ++mj) {
                const int row = wj * 64 + mj * 16 + fr;
                const int sx  = ((kk * 4 + kg) ^ (row & 7)) * 16;
                af[mj] = *(const bf16x8*)(Ys + row * 128 + sx);
            }
            #pragma unroll
            for (int ni = 0; ni < 4; ++ni) {
                const int row = wi * 64 + ni * 16 + fr;
                const int sx  = ((kk * 4 + kg) ^ (row & 7)) * 16;
                bg[ni] = *(const bf16x8*)(Xs + row * 128 + sx);
            }
            #pragma unroll
            for (int mj = 0; mj < 4; ++mj)
                #pragma unroll
                for (int ni = 0; ni < 4; ++ni)
                    acc[mj][ni] = __builtin_amdgcn_mfma_f32_16x16x32_bf16(
                        af[mj], bg[ni], acc[mj][ni], 0, 0, 0);
        }
        __syncthreads();
    }

    // ---- epilogue: rowsum_i += sum_j exp((S[i][j]-1)/tau) ----
    // D layout (16x16, m89/m91 verified): col n = i = lane&15;
    // row m = j = (lane>>4)*4 + reg. Sum over j: in-thread over mj(4) x reg(4),
    // then shfl_xor(16)+shfl_xor(32) across the 4 lane-groups.
    float part[4];
    #pragma unroll
    for (int ni = 0; ni < 4; ++ni) {
        float s = 0.f;
        #pragma unroll
        for (int mj = 0; mj < 4; ++mj)
            #pragma unroll
            for (int r = 0; r < 4; ++r)
                s += __expf(fmaf(acc[mj][ni][r], INV_T, -INV_T));
        s += __shfl_xor(s, 16);
        s += __shfl_xor(s, 32);
        part[ni] = s;
    }
    // Disjoint per-wj slots (plain stores, no LDS atomics), then combine.
    float (*rowpart2)[BM] = (float (*)[BM])lds;  // 1KB, free after last barrier
    if (l < 16) {
        #pragma unroll
        for (int ni = 0; ni < 4; ++ni)
            rowpart2[wj][wi * 64 + ni * 16 + l] = part[ni];
    }
    __syncthreads();
    if (tid < BM)
        atomicAdd(&rowsum[iBase + tid], rowpart2[0][tid] + rowpart2[1][tid]);
}

// ---------------------------------------------------------------------------
// Kernel C: loss = -mean(Sv - log(rowsum)). Single block, 1024 threads.
// ---------------------------------------------------------------------------
__global__ __launch_bounds__(1024) void lit_finish(
    const float* __restrict__ Sv, const float* __restrict__ rowsum,
    float* __restrict__ out, int N)
{
    float s = 0.f;
    for (int i = threadIdx.x; i < N; i += 1024)
        s += Sv[i] - __logf(rowsum[i]);
    #pragma unroll
    for (int o = 1; o < 64; o <<= 1) s += __shfl_xor(s, o);
    __shared__ float sred[16];
    if ((threadIdx.x & 63) == 0) sred[threadIdx.x >> 6] = s;
    __syncthreads();
    if (threadIdx.x == 0) {
        float tot = 0.f;
        #pragma unroll
        for (int k = 0; k < 16; ++k) tot += sred[k];
        out[0] = -tot / (float)N;
    }
}

// ---------------------------------------------------------------------------
extern "C" void kernel_launch(void* const* d_in, const int* in_sizes, int n_in,
                              void* d_out, int out_size, void* d_ws, size_t ws_size,
                              hipStream_t stream)
{
    const float* X = (const float*)d_in[0];
    const float* Y = (const float*)d_in[1];
    const int N = in_sizes[0] / D_DIM;  // 16384

    char* ws = (char*)d_ws;
    __hip_bfloat16* Xb = (__hip_bfloat16*)ws;
    __hip_bfloat16* Yb = (__hip_bfloat16*)(ws + (size_t)N * D_DIM * 2);
    float* Sv     = (float*)(ws + (size_t)N * D_DIM * 4);
    float* rowsum = (float*)(ws + (size_t)N * D_DIM * 4 + (size_t)N * 4);

    lit_normalize<<<N / 4, 256, 0, stream>>>(X, Y, Xb, Yb, Sv, rowsum);
    dim3 grid(N / BN, N / BM);
    lit_gemm_rowsum<<<grid, 256, 0, stream>>>(Xb, Yb, rowsum);
    lit_finish<<<1, 1024, 0, stream>>>(Sv, rowsum, (float*)d_out, N);
}

// Round 10
// 218.538 us; speedup vs baseline: 1.1658x; 1.0557x over previous
//
#include <hip/hip_runtime.h>
#include <hip/hip_bf16.h>
#include <stdint.h>

#define D_DIM 256
#define INV_T 14.285714285714286f  // 1/0.07

#define BM 128   // i-rows per block
#define BN 128   // j-rows per block
#define BK 64
#define NSTEP (D_DIM / BK)  // 4

typedef __bf16 bf16x8 __attribute__((ext_vector_type(8)));
typedef float f32x4 __attribute__((ext_vector_type(4)));

// ---------------------------------------------------------------------------
// Kernel A: normalization. One wave per row (float4 loads), 4 rows/block.
// Exact fp32 diagonal Sv, bf16 normalized outputs, rowsum zero-init.
// ---------------------------------------------------------------------------
__global__ __launch_bounds__(256) void lit_normalize(
    const float* __restrict__ X, const float* __restrict__ Y,
    __hip_bfloat16* __restrict__ Xb, __hip_bfloat16* __restrict__ Yb,
    float* __restrict__ Sv, float* __restrict__ rowsum)
{
    const int l = threadIdx.x & 63;
    const int row = blockIdx.x * 4 + (threadIdx.x >> 6);
    const size_t base = (size_t)row * D_DIM;
    const float4 x = ((const float4*)(X + base))[l];
    const float4 y = ((const float4*)(Y + base))[l];
    float nx = x.x * x.x + x.y * x.y + x.z * x.z + x.w * x.w;
    float ny = y.x * y.x + y.y * y.y + y.z * y.z + y.w * y.w;
    float dt = x.x * y.x + x.y * y.y + x.z * y.z + x.w * y.w;
    #pragma unroll
    for (int o = 1; o < 64; o <<= 1) {
        nx += __shfl_xor(nx, o);
        ny += __shfl_xor(ny, o);
        dt += __shfl_xor(dt, o);
    }
    const float ivx = 1.0f / fmaxf(sqrtf(nx), 1e-12f);
    const float ivy = 1.0f / fmaxf(sqrtf(ny), 1e-12f);

    __hip_bfloat16 hx0 = __float2bfloat16(x.x * ivx), hx1 = __float2bfloat16(x.y * ivx);
    __hip_bfloat16 hx2 = __float2bfloat16(x.z * ivx), hx3 = __float2bfloat16(x.w * ivx);
    __hip_bfloat16 hy0 = __float2bfloat16(y.x * ivy), hy1 = __float2bfloat16(y.y * ivy);
    __hip_bfloat16 hy2 = __float2bfloat16(y.z * ivy), hy3 = __float2bfloat16(y.w * ivy);
    ushort4 px, py;
    px.x = *(unsigned short*)&hx0; px.y = *(unsigned short*)&hx1;
    px.z = *(unsigned short*)&hx2; px.w = *(unsigned short*)&hx3;
    py.x = *(unsigned short*)&hy0; py.y = *(unsigned short*)&hy1;
    py.z = *(unsigned short*)&hy2; py.w = *(unsigned short*)&hy3;
    ((ushort4*)(Xb + base))[l] = px;
    ((ushort4*)(Yb + base))[l] = py;

    if (l == 0) {
        Sv[row] = (dt * ivx * ivy - 1.0f) * INV_T;  // exact diagonal logit
        rowsum[row] = 0.0f;
    }
}

// ---------------------------------------------------------------------------
// Kernel B: round-9 structure UNCHANGED (128x128 tile, 4 waves, 16x16x32,
// swapped operands D = mfma(Yf, Xf) -> j-reduction in-thread, BK=64 single
// 32KB buffer, write-side pre-swizzle slot^= (row&7), 0 bank conflicts,
// 4 blocks/CU). ONLY change vs round 9: L2 super-tiled block-index remap.
//
// Round-9 PMC: FETCH 528 MB @ 3.58 TB/s (45% peak) = largest floor (~84 us).
// Cause: each XCD swept its 16 block-rows ROW-MAJOR -> the 8 MB Y operand
// re-streamed through the 4 MB XCD L2 ~16x. Remap: within an XCD's chunk,
// iterate 4-column groups x 16 rows: Y group (256 KB) + X panels (1 MB)
// stay L2-resident; ideal fetch ~9 MB/XCD = 72 MB total.
// Mapping (bijective, N=16384: grid 128x128, 2048 blocks/XCD):
//   xcd = bid & 7; c = bid >> 3;
//   bjo = c >> 6; bil = (c & 63) >> 2; bji = c & 3;
//   bi = xcd*16 + bil; bj = bjo*4 + bji.
// ---------------------------------------------------------------------------
__global__ __launch_bounds__(256, 4) void lit_gemm_rowsum(
    const __hip_bfloat16* __restrict__ Xb, const __hip_bfloat16* __restrict__ Yb,
    float* __restrict__ rowsum)
{
    __shared__ char lds[2 * BM * BK * 2];  // Xs 16KB | Ys 16KB
    char* Xs = lds;
    char* Ys = lds + BM * BK * 2;

    const int tid = (int)threadIdx.x;
    const int l   = tid & 63;
    const int w   = tid >> 6;    // 0..3
    const int wj  = w >> 1;      // 0..1  (j-half: 64 rows of Y)
    const int wi  = w & 1;       // 0..1  (i-half: 64 rows of X)
    const int fr  = l & 15;      // fragment row/col within 16
    const int kg  = l >> 4;      // k-group (8 contiguous k of 32)

    // L2 super-tiled, XCD-aware block remap (see header comment)
    const int bid = (int)blockIdx.y * (int)gridDim.x + (int)blockIdx.x;
    const int xcd = bid & 7;
    const int c   = bid >> 3;          // 0..2047 within this XCD's chunk
    const int bjo = c >> 6;            // 0..31  (column group of 4)
    const int bil = (c & 63) >> 2;     // 0..15  (row within XCD's 16 rows)
    const int bji = c & 3;             // 0..3   (column within group)
    const int bi  = xcd * 16 + bil;
    const int bj  = bjo * 4 + bji;
    const int iBase = bi * BM;
    const int jBase = bj * BN;

    f32x4 acc[4][4];   // [mj][ni]
    const f32x4 zero = {0.f, 0.f, 0.f, 0.f};
    #pragma unroll
    for (int a = 0; a < 4; ++a)
        #pragma unroll
        for (int b = 0; b < 4; ++b)
            acc[a][b] = zero;

    // Staging: per K-step each wave issues 8 gloads; wave w owns X rows
    // w*32..w*32+31 and Y rows w*32..w*32+31.
    const int rq = l >> 3;   // row within an 8-row chunk
    const int sl = l & 7;    // 16B slot within a 128B row
    const char* srcX[4]; const char* srcY[4];
    int dstX[4], dstY[4];
    #pragma unroll
    for (int i = 0; i < 4; ++i) {
        const int row  = w * 32 + i * 8 + rq;
        const int slot = sl ^ (row & 7);  // pre-swizzled source slot
        srcX[i] = (const char*)Xb + (size_t)(iBase + row) * (D_DIM * 2) + slot * 16;
        srcY[i] = (const char*)Yb + (size_t)(jBase + row) * (D_DIM * 2) + slot * 16;
        dstX[i] = (w * 32 + i * 8) * 128;
        dstY[i] = BM * BK * 2 + (w * 32 + i * 8) * 128;
    }

    #pragma unroll
    for (int t = 0; t < NSTEP; ++t) {
        #pragma unroll
        for (int i = 0; i < 4; ++i) {
            __builtin_amdgcn_global_load_lds(
                (const __attribute__((address_space(1))) void*)(srcX[i] + t * (BK * 2)),
                (__attribute__((address_space(3))) void*)(lds + dstX[i]), 16, 0, 0);
            __builtin_amdgcn_global_load_lds(
                (const __attribute__((address_space(1))) void*)(srcY[i] + t * (BK * 2)),
                (__attribute__((address_space(3))) void*)(lds + dstY[i]), 16, 0, 0);
        }
        __syncthreads();

        #pragma unroll
        for (int kk = 0; kk < 2; ++kk) {
            // logical 16B k-slot g = kk*4 + kg; physical = g ^ (row&7)
            bf16x8 af[4], bg[4];
            #pragma unroll
            for (int mj = 0; mj < 4; ++mj) {
                const int row = wj * 64 + mj * 16 + fr;
                const int sx  = ((kk * 4 + kg) ^ (row & 7)) * 16;
                af[mj] = *(const bf16x8*)(Ys + row * 128 + sx);
            }
            #pragma unroll
            for (int ni = 0; ni < 4; ++ni) {
                const int row = wi * 64 + ni * 16 + fr;
                const int sx  = ((kk * 4 + kg) ^ (row & 7)) * 16;
                bg[ni] = *(const bf16x8*)(Xs + row * 128 + sx);
            }
            #pragma unroll
            for (int mj = 0; mj < 4; ++mj)
                #pragma unroll
                for (int ni = 0; ni < 4; ++ni)
                    acc[mj][ni] = __builtin_amdgcn_mfma_f32_16x16x32_bf16(
                        af[mj], bg[ni], acc[mj][ni], 0, 0, 0);
        }
        __syncthreads();
    }

    // ---- epilogue: rowsum_i += sum_j exp((S[i][j]-1)/tau) ----
    // D layout (16x16, m89/m91 verified): col n = i = lane&15;
    // row m = j = (lane>>4)*4 + reg. Sum over j: in-thread mj(4) x reg(4),
    // then shfl_xor(16)+shfl_xor(32) across the 4 lane-groups.
    float part[4];
    #pragma unroll
    for (int ni = 0; ni < 4; ++ni) {
        float s = 0.f;
        #pragma unroll
        for (int mj = 0; mj < 4; ++mj)
            #pragma unroll
            for (int r = 0; r < 4; ++r)
                s += __expf(fmaf(acc[mj][ni][r], INV_T, -INV_T));
        s += __shfl_xor(s, 16);
        s += __shfl_xor(s, 32);
        part[ni] = s;
    }
    // Disjoint per-wj slots (plain stores, no LDS atomics), then combine.
    float (*rowpart2)[BM] = (float (*)[BM])lds;  // 1KB, free after last barrier
    if (l < 16) {
        #pragma unroll
        for (int ni = 0; ni < 4; ++ni)
            rowpart2[wj][wi * 64 + ni * 16 + l] = part[ni];
    }
    __syncthreads();
    if (tid < BM)
        atomicAdd(&rowsum[iBase + tid], rowpart2[0][tid] + rowpart2[1][tid]);
}

// ---------------------------------------------------------------------------
// Kernel C: loss = -mean(Sv - log(rowsum)). Single block, 1024 threads.
// ---------------------------------------------------------------------------
__global__ __launch_bounds__(1024) void lit_finish(
    const float* __restrict__ Sv, const float* __restrict__ rowsum,
    float* __restrict__ out, int N)
{
    float s = 0.f;
    for (int i = threadIdx.x; i < N; i += 1024)
        s += Sv[i] - __logf(rowsum[i]);
    #pragma unroll
    for (int o = 1; o < 64; o <<= 1) s += __shfl_xor(s, o);
    __shared__ float sred[16];
    if ((threadIdx.x & 63) == 0) sred[threadIdx.x >> 6] = s;
    __syncthreads();
    if (threadIdx.x == 0) {
        float tot = 0.f;
        #pragma unroll
        for (int k = 0; k < 16; ++k) tot += sred[k];
        out[0] = -tot / (float)N;
    }
}

// ---------------------------------------------------------------------------
extern "C" void kernel_launch(void* const* d_in, const int* in_sizes, int n_in,
                              void* d_out, int out_size, void* d_ws, size_t ws_size,
                              hipStream_t stream)
{
    const float* X = (const float*)d_in[0];
    const float* Y = (const float*)d_in[1];
    const int N = in_sizes[0] / D_DIM;  // 16384

    char* ws = (char*)d_ws;
    __hip_bfloat16* Xb = (__hip_bfloat16*)ws;
    __hip_bfloat16* Yb = (__hip_bfloat16*)(ws + (size_t)N * D_DIM * 2);
    float* Sv     = (float*)(ws + (size_t)N * D_DIM * 4);
    float* rowsum = (float*)(ws + (size_t)N * D_DIM * 4 + (size_t)N * 4);

    lit_normalize<<<N / 4, 256, 0, stream>>>(X, Y, Xb, Yb, Sv, rowsum);
    dim3 grid(N / BN, N / BM);
    lit_gemm_rowsum<<<grid, 256, 0, stream>>>(Xb, Yb, rowsum);
    lit_finish<<<1, 1024, 0, stream>>>(Sv, rowsum, (float*)d_out, N);
}